// Round 11
// baseline (139.747 us; speedup 1.0000x reference)
//
#include <hip/hip_runtime.h>

#define NTAG 32
#define START 30
#define STOP 31
#define LOG2E 1.44269504088896340736f
#define LN2 0.69314718055994530942f

typedef float f2 __attribute__((ext_vector_type(2)));
typedef float f4 __attribute__((ext_vector_type(4)));

__device__ __forceinline__ float fexp2(float x) {
#if __has_builtin(__builtin_amdgcn_exp2f)
    return __builtin_amdgcn_exp2f(x);   // v_exp_f32: 2^x
#else
    return exp2f(x);
#endif
}
__device__ __forceinline__ float flog2(float x) {
#if __has_builtin(__builtin_amdgcn_logf)
    return __builtin_amdgcn_logf(x);    // v_log_f32: log2(x)
#else
    return log2f(x);
#endif
}

// Direction-agnostic half-exchange l <-> l+32 (VALU).  a==b==x on entry ->
// {a,b} = {own, partner} in SOME order.  R8-proven.
__device__ __forceinline__ void plswapf(float &a, float &b) {
#if __has_builtin(__builtin_amdgcn_permlane32_swap)
    auto r = __builtin_amdgcn_permlane32_swap(__float_as_int(a), __float_as_int(b),
                                              false, false);
    a = __int_as_float(r[0]);
    b = __int_as_float(r[1]);
#else
    asm volatile("s_nop 1\n\tv_permlane32_swap_b32 %0, %1" : "+v"(a), "+v"(b));
#endif
}
__device__ __forceinline__ void plswapi(int &a, int &b) {
#if __has_builtin(__builtin_amdgcn_permlane32_swap)
    auto r = __builtin_amdgcn_permlane32_swap(a, b, false, false);
    a = r[0]; b = r[1];
#else
    asm volatile("s_nop 1\n\tv_permlane32_swap_b32 %0, %1" : "+v"(a), "+v"(b));
#endif
}

// packed 2xf32 math (VOP3P)
#define PKMUL(d, s, e) asm("v_pk_mul_f32 %0, %1, %2" : "=v"(d) : "v"(s), "v"(e))
#define PKFMA(d, s, e) asm("v_pk_fma_f32 %0, %1, %2, %0" : "+v"(d) : "v"(s), "v"(e))
#define PKADD(d, x, y) asm("v_pk_add_f32 %0, %1, %2" : "=v"(d) : "v"(x), "v"(y))

#define REPEAT16(M) \
    M(0) M(1) M(2) M(3) M(4) M(5) M(6) M(7) \
    M(8) M(9) M(10) M(11) M(12) M(13) M(14) M(15)

// One FUSED step-pair (one wave advances fwd chain in lanes 0-31 AND bwd
// chain of the SAME batch in lanes 32-63).  Per half: full R6-style 32-term
// dot per lane (16 pk ops) on its own 32-float LDS region; 1 ds_write +
// 8 uniform-per-half ds_read_b128 (2 addrs/instr = free 2-way).  Direction
// handled by predication: fwd S<-(M^T S)*F, bwd S<-M(S*F).
// RN: per-half exact pow2 renorm, k from broadcast Q0.x (half-uniform,
// VALU-only; any uniform k preserves the alpha = ln2*(M2+log2 S) invariant).
// ACT: masked epilogue steps discard the matvec but STILL renorm (exact).
#define STEP_CORE(fraw_, RN, ACT) { \
    const float F_ = fexp2((fraw_) * LOG2E); \
    const float SF_ = S * F_; \
    const float y_ = up ? SF_ : S; \
    *swr = y_; \
    asm volatile("" ::: "memory"); \
    const f4 Q0 = srd4[0], Q1 = srd4[1], Q2 = srd4[2], Q3 = srd4[3], \
             Q4 = srd4[4], Q5 = srd4[5], Q6 = srd4[6], Q7 = srd4[7]; \
    const f2 s0  = __builtin_shufflevector(Q0, Q0, 0, 1), s1  = __builtin_shufflevector(Q0, Q0, 2, 3); \
    const f2 s2  = __builtin_shufflevector(Q1, Q1, 0, 1), s3  = __builtin_shufflevector(Q1, Q1, 2, 3); \
    const f2 s4  = __builtin_shufflevector(Q2, Q2, 0, 1), s5  = __builtin_shufflevector(Q2, Q2, 2, 3); \
    const f2 s6  = __builtin_shufflevector(Q3, Q3, 0, 1), s7  = __builtin_shufflevector(Q3, Q3, 2, 3); \
    const f2 s8  = __builtin_shufflevector(Q4, Q4, 0, 1), s9  = __builtin_shufflevector(Q4, Q4, 2, 3); \
    const f2 s10 = __builtin_shufflevector(Q5, Q5, 0, 1), s11 = __builtin_shufflevector(Q5, Q5, 2, 3); \
    const f2 s12 = __builtin_shufflevector(Q6, Q6, 0, 1), s13 = __builtin_shufflevector(Q6, Q6, 2, 3); \
    const f2 s14 = __builtin_shufflevector(Q7, Q7, 0, 1), s15 = __builtin_shufflevector(Q7, Q7, 2, 3); \
    f2 a0, a1, a2, a3; \
    PKMUL(a0, s0,  E2_0);  PKMUL(a1, s1,  E2_1);  PKMUL(a2, s2,  E2_2);  PKMUL(a3, s3,  E2_3); \
    PKFMA(a0, s4,  E2_4);  PKFMA(a1, s5,  E2_5);  PKFMA(a2, s6,  E2_6);  PKFMA(a3, s7,  E2_7); \
    PKFMA(a0, s8,  E2_8);  PKFMA(a1, s9,  E2_9);  PKFMA(a2, s10, E2_10); PKFMA(a3, s11, E2_11); \
    PKFMA(a0, s12, E2_12); PKFMA(a1, s13, E2_13); PKFMA(a2, s14, E2_14); PKFMA(a3, s15, E2_15); \
    f2 t01, t23, tt; \
    PKADD(t01, a0, a1); PKADD(t23, a2, a3); PKADD(tt, t01, t23); \
    const float r_ = tt.x + tt.y; \
    const float rF_ = r_ * F_; \
    const float val_ = up ? r_ : rF_; \
    S = (ACT) ? val_ : S; \
    if (RN) { \
        const int k_ = ((__float_as_int(Q0.x) >> 23) & 0xff) - 127; \
        S = __int_as_float(__float_as_int(S) - (k_ << 23)); \
        M2i += k_; } }

// main-loop step: consume FS, reload it 16 steps ahead via the rolling
// per-lane byte offset (voff advances +-128/step; reload at voff + 16*step;
// bounds proven in-range for both halves while c+16 <= cf).
#define STEP_RELOAD(FS, RN) { const float fraw_ = FS; \
    { FS = *(const float*)((const char*)frow + (voff + d16)); voff += dStep; } \
    STEP_CORE(fraw_, RN, 1) }

// epilogue step i: masked per half (act = i < rl), always-renorm.
#define STEP_EP(FS, i_) { const float fraw_ = FS; \
    const bool act_ = (i_) < rl; \
    STEP_CORE(fraw_, 1, act_) }

// zero-instruction insurance against E2 remat/spill
#define PIN_E2 \
    asm volatile("" : "+v"(E2_0),  "+v"(E2_1),  "+v"(E2_2),  "+v"(E2_3), \
                      "+v"(E2_4),  "+v"(E2_5),  "+v"(E2_6),  "+v"(E2_7)); \
    asm volatile("" : "+v"(E2_8),  "+v"(E2_9),  "+v"(E2_10), "+v"(E2_11), \
                      "+v"(E2_12), "+v"(E2_13), "+v"(E2_14), "+v"(E2_15));

// Block = 512 threads = 8 waves, grid = B/4 = 256 blocks = 1 block/CU.
// Waves 0-3: FUSED chains, one batch each (lanes 0-31 fwd, 32-63 bwd; meet
// at h=(n+1)/2; combine in-wave via permlane32_swap).  Waves 4-7: gold.
// One chain wave per SIMD doing ~40 instr/step-pair replaces R8's two waves
// at 54 instr/pair that did not overlap (424 = 2x212 cy measured).
__global__ __launch_bounds__(512, 1) void crf_nll_kernel(
    const float* __restrict__ feats,   // B x L x 32
    const float* __restrict__ trans,   // 32 x 32
    const int*   __restrict__ tags,    // B x L
    const int*   __restrict__ wsl,     // B
    float* __restrict__ out, int B, int L)
{
    __shared__ float strans[NTAG * NTAG];
    __shared__ __align__(16) float sBC[4][2][NTAG];   // [wave][half][tag]
    for (int i = threadIdx.x; i < NTAG * NTAG; i += 512) strans[i] = trans[i];
    __syncthreads();

    const int wave = threadIdx.x >> 6;
    const int lane = threadIdx.x & 63;

    if (wave < 4) {
        // ================= fused chain wave (one batch) =====================
        int b = blockIdx.x * 4 + wave;
        const int bok = (b < B);
        if (!bok) b = B - 1;
        b = __builtin_amdgcn_readfirstlane(b);

        const int j = lane & 31;
        const bool up = lane >= 32;           // upper half = backward chain
        const int n = __builtin_amdgcn_readfirstlane(wsl[b]);
        const int h = (n + 1) >> 1;           // meet point
        const int cf = h - 1;                 // fwd step count (t = 1..h-1)
        const int cb = n - h;                 // bwd step count (t = n-1..h); cb-cf in {0,1}
        const int climit = up ? cb : cf;
        const float* __restrict__ frow = feats + (size_t)b * L * NTAG;

        // per-half linear transition pairs:
        // fwd: E2_k = {e^T[2k][j], e^T[2k+1][j]}   (column j of M)
        // bwd: E2_k = {e^T[j][2k], e^T[j][2k+1]}   (row j of M)
#define DECL_E2(k) f2 E2_##k = { \
        fexp2(strans[up ? (j * NTAG + 2*(k))     : ((2*(k)) * NTAG + j)]     * LOG2E), \
        fexp2(strans[up ? (j * NTAG + 2*(k) + 1) : ((2*(k)+1) * NTAG + j)] * LOG2E) };
        REPEAT16(DECL_E2)
#undef DECL_E2

        // init: fwd S = 2^((trans[START][j]+feat0_j)*l2e); bwd S = u_j
        const float s0v = up ? strans[j * NTAG + STOP]
                             : (strans[START * NTAG + j] + frow[j]);
        float S = fexp2(s0v * LOG2E);
        int M2i = 0;

        float* const swr = &sBC[wave][up][j];
        const f4* const srd4 = (const f4*)&sBC[wave][up][0];

        // rolling per-lane byte offset into frow: step c consumes time
        // (fwd: c+1, bwd: n-1-c); advances +-128 B/step.
        int voff = ((up ? (n - 1) : 1) * NTAG + j) * 4;
        const int dStep = up ? -(NTAG * 4) : (NTAG * 4);
        const int d16 = dStep * 16;

        // 16 named prefetch slots: slot i = feat for step i (clamped init)
#define LDI(i_) frow[(up ? ((n - 1 - (i_)) > 0 ? (n - 1 - (i_)) : 0) : (1 + (i_))) * NTAG + j]
        float fA0 = LDI(0),  fA1 = LDI(1),  fA2 = LDI(2),  fA3 = LDI(3),
              fA4 = LDI(4),  fA5 = LDI(5),  fA6 = LDI(6),  fA7 = LDI(7);
        float fB0 = LDI(8),  fB1 = LDI(9),  fB2 = LDI(10), fB3 = LDI(11),
              fB4 = LDI(12), fB5 = LDI(13), fB6 = LDI(14), fB7 = LDI(15);
#undef LDI

        int c = 0;
        for (; c + 16 <= cf; c += 16) {       // both halves fully active here
            PIN_E2
            STEP_RELOAD(fA0, 0)
            STEP_RELOAD(fA1, 0)
            STEP_RELOAD(fA2, 0)
            STEP_RELOAD(fA3, 1)               // exact pow2 renorm /4
            STEP_RELOAD(fA4, 0)
            STEP_RELOAD(fA5, 0)
            STEP_RELOAD(fA6, 0)
            STEP_RELOAD(fA7, 1)
            STEP_RELOAD(fB0, 0)
            STEP_RELOAD(fB1, 0)
            STEP_RELOAD(fB2, 0)
            STEP_RELOAD(fB3, 1)
            STEP_RELOAD(fB4, 0)
            STEP_RELOAD(fB5, 0)
            STEP_RELOAD(fB6, 0)
            STEP_RELOAD(fB7, 1)
        }
        // epilogue: up to 16 masked steps (rl = remaining per half; cb-cf<=1
        // so bwd may run one step past fwd; masked half discards matvec,
        // renorm still applies - invariant-preserving).
        {
            const int rl = climit - c;
            STEP_EP(fA0, 0)
            STEP_EP(fA1, 1)
            STEP_EP(fA2, 2)
            STEP_EP(fA3, 3)
            STEP_EP(fA4, 4)
            STEP_EP(fA5, 5)
            STEP_EP(fA6, 6)
            STEP_EP(fA7, 7)
            STEP_EP(fB0, 8)
            STEP_EP(fB1, 9)
            STEP_EP(fB2, 10)
            STEP_EP(fB3, 11)
            STEP_EP(fB4, 12)
            STEP_EP(fB5, 13)
            STEP_EP(fB6, 14)
            STEP_EP(fB7, 15)
        }

        // ===== in-wave combine: score = ln2*(M2f+M2b+log2 sum_j Sf_j*Sb_j) ==
        float pa = S, pb = S;
        plswapf(pa, pb);                      // {own, partner} either order
        float prod = pa * pb;                 // = Sf_j * Sb_j in both halves
#pragma unroll
        for (int k = 1; k < 32; k <<= 1) prod += __shfl_xor(prod, k, 32);
        int ma = M2i, mb = M2i;
        plswapi(ma, mb);
        const int M2tot = ma + mb;            // = M2f + M2b (all lanes)
        if (lane == 0 && bok)
            atomicAdd(out, LN2 * ((float)M2tot + flog2(prod)));
    } else {
        // ================= gold waves (pure gathers) ========================
        int b = blockIdx.x * 4 + (wave - 4);
        if (b < B) {
            b = __builtin_amdgcn_readfirstlane(b);
            const int n = wsl[b];
            const float* __restrict__ frow = feats + (size_t)b * L * NTAG;
            const int*   __restrict__ trow = tags  + (size_t)b * L;
            float acc = 0.f;
            for (int tt = lane; tt < L; tt += 64) {
                const int tg = trow[tt];
                if (tt == 0) {
                    acc += strans[START * NTAG + tg] + frow[tg];
                } else if (tt < n) {
                    const int tgp = trow[tt - 1];
                    acc += strans[tgp * NTAG + tg] + frow[tt * NTAG + tg];
                }
                if (tt == n - 1) {
                    acc += strans[tg * NTAG + STOP];
                }
            }
#pragma unroll
            for (int k = 1; k < 64; k <<= 1) acc += __shfl_xor(acc, k, 64);
            if (lane == 0) atomicAdd(out, -acc);
        }
    }
}

extern "C" void kernel_launch(void* const* d_in, const int* in_sizes, int n_in,
                              void* d_out, int out_size, void* d_ws, size_t ws_size,
                              hipStream_t stream) {
    const float* feats = (const float*)d_in[0];
    const float* trans = (const float*)d_in[1];
    const int*   tags  = (const int*)d_in[2];
    const int*   wsl   = (const int*)d_in[3];
    float* out = (float*)d_out;

    const int B = in_sizes[3];              // word_seq_lens: (B,)
    const int L = in_sizes[2] / B;          // tags: (B, L)

    (void)hipMemsetAsync(out, 0, sizeof(float), stream);
    const int grid = (B + 3) / 4;
    crf_nll_kernel<<<grid, 512, 0, stream>>>(feats, trans, tags, wsl, out, B, L);
}

// Round 12
// 125.879 us; speedup vs baseline: 1.1102x; 1.1102x over previous
//
#include <hip/hip_runtime.h>

#define NTAG 32
#define START 30
#define STOP 31
#define LOG2E 1.44269504088896340736f
#define LN2 0.69314718055994530942f

typedef float f2 __attribute__((ext_vector_type(2)));
typedef float f4 __attribute__((ext_vector_type(4)));

__device__ __forceinline__ float fexp2(float x) {
#if __has_builtin(__builtin_amdgcn_exp2f)
    return __builtin_amdgcn_exp2f(x);   // v_exp_f32: 2^x
#else
    return exp2f(x);
#endif
}
__device__ __forceinline__ float flog2(float x) {
#if __has_builtin(__builtin_amdgcn_logf)
    return __builtin_amdgcn_logf(x);    // v_log_f32: log2(x)
#else
    return log2f(x);
#endif
}

// packed 2xf32 math (VOP3P)
#define PKMUL(d, s, e) asm("v_pk_mul_f32 %0, %1, %2" : "=v"(d) : "v"(s), "v"(e))
#define PKFMA(d, s, e) asm("v_pk_fma_f32 %0, %1, %2, %0" : "+v"(d) : "v"(s), "v"(e))
#define PKADD(d, x, y) asm("v_pk_add_f32 %0, %1, %2" : "=v"(d) : "v"(x), "v"(y))

#define REPEAT8(M) M(0) M(1) M(2) M(3) M(4) M(5) M(6) M(7)

// One LINEAR-domain step, dot product SPLIT across wave halves (R8-proven):
// lanes j and j+32 both own output j; lane j handles input terms 0..15,
// lane j+32 terms 16..31.  Broadcast: lower lanes write the 32 state values
// to LDS; each half reads back only ITS 16 inputs (4x ds_read_b128; the two
// per-instr uniform addresses are 64B apart = bank-disjoint).  Cross-half
// combine via permlane32_swap (VALU).  PRE=0 fwd: S <- (M^T S)*F;
// PRE=1 bwd: S <- M(S*F).  RN: WAVE-UNIFORM exact pow2 renorm, k from the
// broadcast Q0.x (uniform within wave since both replicas are bitwise
// identical); per-lane k is WRONG (R7 regression).
#define STEP_CORE(fraw_, PRE, RN) { \
    const float F_ = fexp2((fraw_) * LOG2E); \
    const float y_ = (PRE) ? (S * F_) : S; \
    *swr = y_; \
    asm volatile("" ::: "memory"); \
    const f4 Q0 = srd4[0], Q1 = srd4[1], Q2 = srd4[2], Q3 = srd4[3]; \
    const f2 s0 = __builtin_shufflevector(Q0, Q0, 0, 1), s1 = __builtin_shufflevector(Q0, Q0, 2, 3); \
    const f2 s2 = __builtin_shufflevector(Q1, Q1, 0, 1), s3 = __builtin_shufflevector(Q1, Q1, 2, 3); \
    const f2 s4 = __builtin_shufflevector(Q2, Q2, 0, 1), s5 = __builtin_shufflevector(Q2, Q2, 2, 3); \
    const f2 s6 = __builtin_shufflevector(Q3, Q3, 0, 1), s7 = __builtin_shufflevector(Q3, Q3, 2, 3); \
    f2 a0, a1, a2, a3; \
    PKMUL(a0, s0, E2_0); PKMUL(a1, s1, E2_1); PKMUL(a2, s2, E2_2); PKMUL(a3, s3, E2_3); \
    PKFMA(a0, s4, E2_4); PKFMA(a1, s5, E2_5); PKFMA(a2, s6, E2_6); PKFMA(a3, s7, E2_7); \
    f2 t01, t23, tt; \
    PKADD(t01, a0, a1); PKADD(t23, a2, a3); PKADD(tt, t01, t23); \
    const float part_ = tt.x + tt.y; \
    float px_ = part_, py_ = part_; \
    plswap(px_, py_); \
    const float r_ = px_ + py_; \
    S = (PRE) ? r_ : (r_ * F_); \
    if (RN) { \
        const int k_ = ((__float_as_int(Q0.x) >> 23) & 0xff) - 127; \
        S = __int_as_float(__float_as_int(S) - (k_ << 23)); \
        M2i += k_; } }

// Half-exchange (v_permlane32_swap_b32, VALU).  a==b==x on entry ->
// {a,b} = {own, partner} in SOME order -> a+b direction-proof.  R8-proven.
__device__ __forceinline__ void plswap(float &a, float &b) {
#if __has_builtin(__builtin_amdgcn_permlane32_swap)
    auto r = __builtin_amdgcn_permlane32_swap(__float_as_int(a), __float_as_int(b),
                                              false, false);
    a = __int_as_float(r[0]);
    b = __int_as_float(r[1]);
#else
    asm volatile("v_permlane32_swap_b32 %0, %1" : "+v"(a), "+v"(b));
#endif
}

// main-loop reload: rolling per-lane byte offset (no mul/clamp; bounds
// proven: fwd reload times 17..h+15 <= 271 < L; bwd reload times
// n-17..h-16 >= 0 whenever the main loop runs (cnt>=16 -> h>=16)).
#define STEP_RELOAD(FS, PRE, RN) { const float fraw_ = FS; \
    { FS = *(const float*)((const char*)frow + voff); voff += dStep; } \
    STEP_CORE(fraw_, PRE, RN) }

#define STEP_NR(FS, PRE, RN) { const float fraw_ = FS; STEP_CORE(fraw_, PRE, RN) }

// zero-instruction insurance against E2 remat/spill
#define PIN_E2 \
    asm volatile("" : "+v"(E2_0), "+v"(E2_1), "+v"(E2_2), "+v"(E2_3), \
                      "+v"(E2_4), "+v"(E2_5), "+v"(E2_6), "+v"(E2_7));

// Block = 768 threads = 12 waves, grid = B/4 = 256 blocks = 1 block/CU.
// Waves 0-3: FORWARD half-chains (batch blk*4+w, split-dot, 64 lanes).
// Waves 4-7: BACKWARD half-chains.  Waves 8-11: gold gathers.
// SIMD s hosts fwd(b_s) + bwd(b_s) + gold: the two chain waves' DS waits
// overlap near-perfectly (R11 evidence: pair 424 ~ max(solo, solo)).
__global__ __launch_bounds__(768, 1) void crf_nll_kernel(
    const float* __restrict__ feats,   // B x L x 32
    const float* __restrict__ trans,   // 32 x 32
    const int*   __restrict__ tags,    // B x L
    const int*   __restrict__ wsl,     // B
    float* __restrict__ out, int B, int L)
{
    __shared__ float strans[NTAG * NTAG];
    __shared__ __align__(16) float sBC[8][104]; // [wave]: state [0..31], dummy [68..99]
    __shared__ float sRes[8][NTAG];    // fwd S (0-3), bwd x (4-7)
    __shared__ int   sM2[8];           // per-wave renorm exponent (uniform)
    for (int i = threadIdx.x; i < NTAG * NTAG; i += 768) strans[i] = trans[i];
    __syncthreads();

    const int wave = threadIdx.x >> 6;
    const int lane = threadIdx.x & 63;

    if (wave < 8) {
        const int dir = wave >> 2;            // 0 = fwd, 1 = bwd
        int b = blockIdx.x * 4 + (wave & 3);
        if (b >= B) b = B - 1;
        b = __builtin_amdgcn_readfirstlane(b);
        const int j = lane & 31;
        const bool up = lane >= 32;
        const int ib = up ? 16 : 0;           // this half's input-term base
        const int n = __builtin_amdgcn_readfirstlane(wsl[b]);
        const int h = (n + 1) >> 1;           // meet point
        const float* __restrict__ frow = feats + (size_t)b * L * NTAG;

        float* const swr = &sBC[wave][(up ? 68 : 0) + j];       // write slot (dummy for upper)
        const f4* const srd4 = (const f4*)&sBC[wave][up ? 16 : 0]; // this half's 16 inputs
        float S;
        int M2i = 0;

        if (dir == 0) {
            // ========== forward: S(0) -> S(h-1), cnt = h-1 steps ============
#define DECL_E2(k) f2 E2_##k = { fexp2(strans[(ib + 2*(k)) * NTAG + j] * LOG2E), \
                                 fexp2(strans[(ib + 2*(k) + 1) * NTAG + j] * LOG2E) };
            REPEAT8(DECL_E2)
#undef DECL_E2
            S = fexp2((strans[START * NTAG + j] + frow[j]) * LOG2E);
            int voff = (17 * NTAG + j) * 4;   // first reload = time 17
            const int dStep = NTAG * 4;
#define LDF(t_) frow[(((t_) < L - 1) ? (t_) : (L - 1)) * NTAG + j]
            float fA0 = LDF(1),  fA1 = LDF(2),  fA2 = LDF(3),  fA3 = LDF(4),
                  fA4 = LDF(5),  fA5 = LDF(6),  fA6 = LDF(7),  fA7 = LDF(8);
            float fB0 = LDF(9),  fB1 = LDF(10), fB2 = LDF(11), fB3 = LDF(12),
                  fB4 = LDF(13), fB5 = LDF(14), fB6 = LDF(15), fB7 = LDF(16);
#undef LDF
            int t = 1;
            for (; t + 16 <= h; t += 16) {
                PIN_E2
                STEP_RELOAD(fA0, 0, 0)
                STEP_RELOAD(fA1, 0, 0)
                STEP_RELOAD(fA2, 0, 0)
                STEP_RELOAD(fA3, 0, 0)
                STEP_RELOAD(fA4, 0, 0)
                STEP_RELOAD(fA5, 0, 0)
                STEP_RELOAD(fA6, 0, 0)
                STEP_RELOAD(fA7, 0, 1)        // exact pow2 renorm /8
                STEP_RELOAD(fB0, 0, 0)
                STEP_RELOAD(fB1, 0, 0)
                STEP_RELOAD(fB2, 0, 0)
                STEP_RELOAD(fB3, 0, 0)
                STEP_RELOAD(fB4, 0, 0)
                STEP_RELOAD(fB5, 0, 0)
                STEP_RELOAD(fB6, 0, 0)
                STEP_RELOAD(fB7, 0, 1)
            }
            if (t + 0  < h) { STEP_NR(fA0, 0, 1) }
            if (t + 1  < h) { STEP_NR(fA1, 0, 1) }
            if (t + 2  < h) { STEP_NR(fA2, 0, 1) }
            if (t + 3  < h) { STEP_NR(fA3, 0, 1) }
            if (t + 4  < h) { STEP_NR(fA4, 0, 1) }
            if (t + 5  < h) { STEP_NR(fA5, 0, 1) }
            if (t + 6  < h) { STEP_NR(fA6, 0, 1) }
            if (t + 7  < h) { STEP_NR(fA7, 0, 1) }
            if (t + 8  < h) { STEP_NR(fB0, 0, 1) }
            if (t + 9  < h) { STEP_NR(fB1, 0, 1) }
            if (t + 10 < h) { STEP_NR(fB2, 0, 1) }
            if (t + 11 < h) { STEP_NR(fB3, 0, 1) }
            if (t + 12 < h) { STEP_NR(fB4, 0, 1) }
            if (t + 13 < h) { STEP_NR(fB5, 0, 1) }
            if (t + 14 < h) { STEP_NR(fB6, 0, 1) }
        } else {
            // ========== backward: x = u, t = n-1 .. h, cnt = n-h ============
#define DECL_E2(k) f2 E2_##k = { fexp2(strans[j * NTAG + ib + 2*(k)] * LOG2E), \
                                 fexp2(strans[j * NTAG + ib + 2*(k) + 1] * LOG2E) };
            REPEAT8(DECL_E2)
#undef DECL_E2
            S = fexp2(strans[j * NTAG + STOP] * LOG2E);   // u_j
            const int cnt = n - h;
            int voff = ((n - 17) * NTAG + j) * 4;   // first reload = time n-17
            const int dStep = -(NTAG * 4);
#define LDB(s_) frow[(((n - 1 - (s_)) > 0) ? (n - 1 - (s_)) : 0) * NTAG + j]
            float gA0 = LDB(0),  gA1 = LDB(1),  gA2 = LDB(2),  gA3 = LDB(3),
                  gA4 = LDB(4),  gA5 = LDB(5),  gA6 = LDB(6),  gA7 = LDB(7);
            float gB0 = LDB(8),  gB1 = LDB(9),  gB2 = LDB(10), gB3 = LDB(11),
                  gB4 = LDB(12), gB5 = LDB(13), gB6 = LDB(14), gB7 = LDB(15);
#undef LDB
            int s = 0;
            for (; s + 16 <= cnt; s += 16) {
                PIN_E2
                STEP_RELOAD(gA0, 1, 0)
                STEP_RELOAD(gA1, 1, 0)
                STEP_RELOAD(gA2, 1, 0)
                STEP_RELOAD(gA3, 1, 0)
                STEP_RELOAD(gA4, 1, 0)
                STEP_RELOAD(gA5, 1, 0)
                STEP_RELOAD(gA6, 1, 0)
                STEP_RELOAD(gA7, 1, 1)        // exact pow2 renorm /8
                STEP_RELOAD(gB0, 1, 0)
                STEP_RELOAD(gB1, 1, 0)
                STEP_RELOAD(gB2, 1, 0)
                STEP_RELOAD(gB3, 1, 0)
                STEP_RELOAD(gB4, 1, 0)
                STEP_RELOAD(gB5, 1, 0)
                STEP_RELOAD(gB6, 1, 0)
                STEP_RELOAD(gB7, 1, 1)
            }
            if (s + 0  < cnt) { STEP_NR(gA0, 1, 1) }
            if (s + 1  < cnt) { STEP_NR(gA1, 1, 1) }
            if (s + 2  < cnt) { STEP_NR(gA2, 1, 1) }
            if (s + 3  < cnt) { STEP_NR(gA3, 1, 1) }
            if (s + 4  < cnt) { STEP_NR(gA4, 1, 1) }
            if (s + 5  < cnt) { STEP_NR(gA5, 1, 1) }
            if (s + 6  < cnt) { STEP_NR(gA6, 1, 1) }
            if (s + 7  < cnt) { STEP_NR(gA7, 1, 1) }
            if (s + 8  < cnt) { STEP_NR(gB0, 1, 1) }
            if (s + 9  < cnt) { STEP_NR(gB1, 1, 1) }
            if (s + 10 < cnt) { STEP_NR(gB2, 1, 1) }
            if (s + 11 < cnt) { STEP_NR(gB3, 1, 1) }
            if (s + 12 < cnt) { STEP_NR(gB4, 1, 1) }
            if (s + 13 < cnt) { STEP_NR(gB5, 1, 1) }
            if (s + 14 < cnt) { STEP_NR(gB6, 1, 1) }
        }
        if (!up) {
            sRes[wave][j] = S;
            if (j == 0) sM2[wave] = M2i;
        }
    } else {
        // ================= gold waves (pure gathers) ========================
        int b = blockIdx.x * 4 + (wave - 8);
        if (b < B) {
            b = __builtin_amdgcn_readfirstlane(b);
            const int n = wsl[b];
            const float* __restrict__ frow = feats + (size_t)b * L * NTAG;
            const int*   __restrict__ trow = tags  + (size_t)b * L;
            float acc = 0.f;
            for (int tt = lane; tt < L; tt += 64) {
                const int tg = trow[tt];
                if (tt == 0) {
                    acc += strans[START * NTAG + tg] + frow[tg];
                } else if (tt < n) {
                    const int tgp = trow[tt - 1];
                    acc += strans[tgp * NTAG + tg] + frow[tt * NTAG + tg];
                }
                if (tt == n - 1) {
                    acc += strans[tg * NTAG + STOP];
                }
            }
#pragma unroll
            for (int k = 1; k < 64; k <<= 1) acc += __shfl_xor(acc, k, 64);
            if (lane == 0) atomicAdd(out, -acc);
        }
    }

    __syncthreads();

    // ============== combine: forward score = ln2*(M2f+M2b+log2(x . S)) ======
    if (wave < 4) {
        const int b2 = blockIdx.x * 4 + wave;
        if (b2 < B && lane < 32) {
            float ex = sRes[wave][lane] * sRes[wave + 4][lane];
#pragma unroll
            for (int k = 1; k < 32; k <<= 1) ex += __shfl_xor(ex, k, 32);
            if (lane == 0)
                atomicAdd(out, LN2 * ((float)(sM2[wave] + sM2[wave + 4]) + flog2(ex)));
        }
    }
}

extern "C" void kernel_launch(void* const* d_in, const int* in_sizes, int n_in,
                              void* d_out, int out_size, void* d_ws, size_t ws_size,
                              hipStream_t stream) {
    const float* feats = (const float*)d_in[0];
    const float* trans = (const float*)d_in[1];
    const int*   tags  = (const int*)d_in[2];
    const int*   wsl   = (const int*)d_in[3];
    float* out = (float*)d_out;

    const int B = in_sizes[3];              // word_seq_lens: (B,)
    const int L = in_sizes[2] / B;          // tags: (B, L)

    (void)hipMemsetAsync(out, 0, sizeof(float), stream);
    const int grid = (B + 3) / 4;
    crf_nll_kernel<<<grid, 768, 0, stream>>>(feats, trans, tags, wsl, out, B, L);
}